// Round 1
// baseline (122.251 us; speedup 1.0000x reference)
//
#include <hip/hip_runtime.h>

#define BB 4
#define DD 81
#define HH 256
#define WW 256
#define HW (HH*WW)

// ---------------------------------------------------------------------------
// Kernel 1: cmin[b,h,w] = min over d of cost[b,d,h,w]
// float4 over the W axis; consecutive threads -> consecutive float4 (coalesced)
// ---------------------------------------------------------------------------
__global__ void k_cmin(const float* __restrict__ cost, float* __restrict__ cmin) {
    int i = blockIdx.x * blockDim.x + threadIdx.x;   // over B*HW/4
    const int n = BB * HW / 4;
    if (i >= n) return;
    int b   = i / (HW / 4);
    int hw4 = i % (HW / 4);
    const float4* src = reinterpret_cast<const float4*>(cost + (size_t)b * DD * HW) + hw4;
    float4 m = src[0];
    #pragma unroll 1
    for (int d = 1; d < DD; ++d) {
        float4 v = src[(size_t)d * (HW / 4)];
        m.x = fminf(m.x, v.x);
        m.y = fminf(m.y, v.y);
        m.z = fminf(m.z, v.z);
        m.w = fminf(m.w, v.w);
    }
    reinterpret_cast<float4*>(cmin)[i] = m;
}

// ---------------------------------------------------------------------------
// Kernel 2: scalar directional scans.
//   m_w = cmin_w + e_w * m_{w-1};   contribution at w is e_w * m_{w-1}
// threads [0, B*H)      : horizontal rows, forward (edge ch 0) + backward (ch 1) -> gh
// threads [B*H, 2*B*H)  : vertical columns, down (ch 2) + up (ch 3)              -> gv
// ---------------------------------------------------------------------------
__global__ void k_scan(const float* __restrict__ cmin, const float* __restrict__ edge,
                       float* __restrict__ gh, float* __restrict__ gv) {
    int t = blockIdx.x * blockDim.x + threadIdx.x;
    if (t < BB * HH) {
        int b = t / HH, h = t % HH;
        const float* cm = cmin + (size_t)b * HW + (size_t)h * WW;
        const float* e0 = edge + ((size_t)b * 4 + 0) * HW + (size_t)h * WW;
        const float* e1 = edge + ((size_t)b * 4 + 1) * HW + (size_t)h * WW;
        float* g = gh + (size_t)b * HW + (size_t)h * WW;
        float m = 0.f;
        for (int w = 0; w < WW; ++w) {
            float c = e0[w] * m;
            g[w] = c;
            m = cm[w] + c;
        }
        m = 0.f;
        for (int w = WW - 1; w >= 0; --w) {
            float c = e1[w] * m;
            g[w] += c;
            m = cm[w] + c;
        }
    } else if (t < 2 * BB * HH) {
        int t2 = t - BB * HH;
        int b = t2 / WW, w = t2 % WW;
        const float* cm = cmin + (size_t)b * HW + w;
        const float* e2 = edge + ((size_t)b * 4 + 2) * HW + w;
        const float* e3 = edge + ((size_t)b * 4 + 3) * HW + w;
        float* g = gv + (size_t)b * HW + w;
        float m = 0.f;
        for (int h = 0; h < HH; ++h) {
            float c = e2[(size_t)h * WW] * m;
            g[(size_t)h * WW] = c;
            m = cm[(size_t)h * WW] + c;
        }
        m = 0.f;
        for (int h = HH - 1; h >= 0; --h) {
            float c = e3[(size_t)h * WW] * m;
            g[(size_t)h * WW] += c;
            m = cm[(size_t)h * WW] + c;
        }
    }
}

// ---------------------------------------------------------------------------
// Kernel 3: out[b,d,h,w] = 4*cost[b,d,h,w] + gh[b,h,w] + gv[b,h,w]
// ---------------------------------------------------------------------------
__global__ void k_out(const float* __restrict__ cost, const float* __restrict__ gh,
                      const float* __restrict__ gv, float* __restrict__ out) {
    int i = blockIdx.x * blockDim.x + threadIdx.x;   // float4 index
    const int n4 = BB * DD * HW / 4;
    if (i >= n4) return;
    int base = i << 2;                    // element index (< 2^25, fits int)
    int b    = base / (DD * HW);
    int rem  = base % (DD * HW);
    int hw   = rem % HW;
    float4 c = reinterpret_cast<const float4*>(cost)[i];
    int gi   = (b * HW + hw) >> 2;
    float4 a = reinterpret_cast<const float4*>(gh)[gi];
    float4 v = reinterpret_cast<const float4*>(gv)[gi];
    float4 o;
    o.x = 4.f * c.x + a.x + v.x;
    o.y = 4.f * c.y + a.y + v.y;
    o.z = 4.f * c.z + a.z + v.z;
    o.w = 4.f * c.w + a.w + v.w;
    reinterpret_cast<float4*>(out)[i] = o;
}

extern "C" void kernel_launch(void* const* d_in, const int* in_sizes, int n_in,
                              void* d_out, int out_size, void* d_ws, size_t ws_size,
                              hipStream_t stream) {
    const float* cost = (const float*)d_in[0];
    const float* edge = (const float*)d_in[1];
    float* out = (float*)d_out;

    // workspace layout: gh [1MB] | gv [1MB] | cmin [1MB]
    float* gh   = (float*)d_ws;
    float* gv   = gh + (size_t)BB * HW;
    float* cmin = gv + (size_t)BB * HW;

    {   // cmin: B*HW/4 = 65536 threads
        int n = BB * HW / 4;
        dim3 blk(256), grd((n + 255) / 256);
        k_cmin<<<grd, blk, 0, stream>>>(cost, cmin);
    }
    {   // scans: 2*B*H = 2048 threads
        int n = 2 * BB * HH;
        dim3 blk(256), grd((n + 255) / 256);
        k_scan<<<grd, blk, 0, stream>>>(cmin, edge, gh, gv);
    }
    {   // output: B*D*HW/4 threads
        int n4 = BB * DD * HW / 4;
        dim3 blk(256), grd((n4 + 255) / 256);
        k_out<<<grd, blk, 0, stream>>>(cost, gh, gv, out);
    }
}

// Round 2
// 63.854 us; speedup vs baseline: 1.9145x; 1.9145x over previous
//
#include <hip/hip_runtime.h>

#define BB 4
#define DD 81
#define HH 256
#define WW 256
#define HW (HH*WW)

// ---------------------------------------------------------------------------
// Kernel 1: cmin[b,h,w] = min over d of cost[b,d,h,w]
// ---------------------------------------------------------------------------
__global__ void k_cmin(const float* __restrict__ cost, float* __restrict__ cmin) {
    int i = blockIdx.x * blockDim.x + threadIdx.x;   // over B*HW/4
    const int n = BB * HW / 4;
    if (i >= n) return;
    int b   = i / (HW / 4);
    int hw4 = i % (HW / 4);
    const float4* src = reinterpret_cast<const float4*>(cost + (size_t)b * DD * HW) + hw4;
    float4 m = src[0];
    #pragma unroll 1
    for (int d = 1; d < DD; ++d) {
        float4 v = src[(size_t)d * (HW / 4)];
        m.x = fminf(m.x, v.x);
        m.y = fminf(m.y, v.y);
        m.z = fminf(m.z, v.z);
        m.w = fminf(m.w, v.w);
    }
    reinterpret_cast<float4*>(cmin)[i] = m;
}

// ---------------------------------------------------------------------------
// Wave-parallel bidirectional linear-recurrence scan over 256 elements.
// Each lane owns 4 consecutive elements. Recurrence m_j = c_j + e_j*m_{j-1},
// operator (a,b): m_out = a*m_in + b; composition cur∘prev =
// (a_c*a_p, a_c*b_p + b_c). g_j = e_j * m_{j-1} accumulated for both dirs.
// ---------------------------------------------------------------------------
__device__ __forceinline__ void wave_scan_bidir(
        int lane, const float c[4], const float ef[4], const float eb[4], float g[4]) {
    // ---- forward (element order: lane asc, j asc) ----
    float A = 1.f, B = 0.f;
    #pragma unroll
    for (int j = 0; j < 4; ++j) { B = ef[j] * B + c[j]; A = ef[j] * A; }
    #pragma unroll
    for (int d = 1; d < 64; d <<= 1) {
        float Ap = __shfl_up(A, d);
        float Bp = __shfl_up(B, d);
        if (lane >= d) { B = A * Bp + B; A = A * Ap; }
    }
    float m_in = __shfl_up(B, 1);
    if (lane == 0) m_in = 0.f;
    float m = m_in;
    #pragma unroll
    for (int j = 0; j < 4; ++j) { float t = ef[j] * m; g[j] = t; m = c[j] + t; }
    // ---- backward (element order: lane desc, j desc) ----
    A = 1.f; B = 0.f;
    #pragma unroll
    for (int j = 3; j >= 0; --j) { B = eb[j] * B + c[j]; A = eb[j] * A; }
    #pragma unroll
    for (int d = 1; d < 64; d <<= 1) {
        float An = __shfl_down(A, d);
        float Bn = __shfl_down(B, d);
        if (lane + d < 64) { B = A * Bn + B; A = A * An; }
    }
    m_in = __shfl_down(B, 1);
    if (lane == 63) m_in = 0.f;
    m = m_in;
    #pragma unroll
    for (int j = 3; j >= 0; --j) { float t = eb[j] * m; g[j] += t; m = c[j] + t; }
}

// ---------------------------------------------------------------------------
// Kernel 2: waves [0,1024): horizontal rows (edge ch 0 fwd, ch 1 bwd) -> gh
//           waves [1024,2048): vertical cols (edge ch 2 down, ch 3 up) -> gv
// ---------------------------------------------------------------------------
__global__ void k_scan(const float* __restrict__ cmin, const float* __restrict__ edge,
                       float* __restrict__ gh, float* __restrict__ gv) {
    int tid  = blockIdx.x * blockDim.x + threadIdx.x;
    int wave = tid >> 6;
    int lane = tid & 63;
    float c[4], ef[4], eb[4], g[4];
    if (wave < BB * HH) {
        int b = wave / HH, h = wave % HH;
        size_t row = (size_t)b * HW + (size_t)h * WW;
        float4 c4  = reinterpret_cast<const float4*>(cmin + row)[lane];
        float4 f4  = reinterpret_cast<const float4*>(edge + ((size_t)b * 4 + 0) * HW + (size_t)h * WW)[lane];
        float4 b4  = reinterpret_cast<const float4*>(edge + ((size_t)b * 4 + 1) * HW + (size_t)h * WW)[lane];
        c[0]=c4.x; c[1]=c4.y; c[2]=c4.z; c[3]=c4.w;
        ef[0]=f4.x; ef[1]=f4.y; ef[2]=f4.z; ef[3]=f4.w;
        eb[0]=b4.x; eb[1]=b4.y; eb[2]=b4.z; eb[3]=b4.w;
        wave_scan_bidir(lane, c, ef, eb, g);
        float4 o = {g[0], g[1], g[2], g[3]};
        reinterpret_cast<float4*>(gh + row)[lane] = o;
    } else if (wave < 2 * BB * HH) {
        int wv = wave - BB * HH;
        int b = wv / WW, w = wv % WW;
        const float* cm = cmin + (size_t)b * HW + w;
        const float* e2 = edge + ((size_t)b * 4 + 2) * HW + w;
        const float* e3 = edge + ((size_t)b * 4 + 3) * HW + w;
        int r0 = lane * 4;
        #pragma unroll
        for (int j = 0; j < 4; ++j) {
            size_t off = (size_t)(r0 + j) * WW;
            c[j]  = cm[off];
            ef[j] = e2[off];
            eb[j] = e3[off];
        }
        wave_scan_bidir(lane, c, ef, eb, g);
        float* go = gv + (size_t)b * HW + w;
        #pragma unroll
        for (int j = 0; j < 4; ++j) go[(size_t)(r0 + j) * WW] = g[j];
    }
}

// ---------------------------------------------------------------------------
// Kernel 3: out[b,d,h,w] = 4*cost[b,d,h,w] + gh[b,h,w] + gv[b,h,w]
// ---------------------------------------------------------------------------
__global__ void k_out(const float* __restrict__ cost, const float* __restrict__ gh,
                      const float* __restrict__ gv, float* __restrict__ out) {
    int i = blockIdx.x * blockDim.x + threadIdx.x;   // float4 index
    const int n4 = BB * DD * HW / 4;
    if (i >= n4) return;
    int base = i << 2;
    int b    = base / (DD * HW);
    int rem  = base % (DD * HW);
    int hw   = rem % HW;
    float4 c = reinterpret_cast<const float4*>(cost)[i];
    int gi   = (b * HW + hw) >> 2;
    float4 a = reinterpret_cast<const float4*>(gh)[gi];
    float4 v = reinterpret_cast<const float4*>(gv)[gi];
    float4 o;
    o.x = 4.f * c.x + a.x + v.x;
    o.y = 4.f * c.y + a.y + v.y;
    o.z = 4.f * c.z + a.z + v.z;
    o.w = 4.f * c.w + a.w + v.w;
    reinterpret_cast<float4*>(out)[i] = o;
}

extern "C" void kernel_launch(void* const* d_in, const int* in_sizes, int n_in,
                              void* d_out, int out_size, void* d_ws, size_t ws_size,
                              hipStream_t stream) {
    const float* cost = (const float*)d_in[0];
    const float* edge = (const float*)d_in[1];
    float* out = (float*)d_out;

    // workspace layout: gh [1MB] | gv [1MB] | cmin [1MB]
    float* gh   = (float*)d_ws;
    float* gv   = gh + (size_t)BB * HW;
    float* cmin = gv + (size_t)BB * HW;

    {   // cmin: B*HW/4 = 65536 threads
        int n = BB * HW / 4;
        k_cmin<<<dim3((n + 255) / 256), dim3(256), 0, stream>>>(cost, cmin);
    }
    {   // scans: 2048 waves = 131072 threads
        int n = 2 * BB * HH * 64;
        k_scan<<<dim3((n + 255) / 256), dim3(256), 0, stream>>>(cmin, edge, gh, gv);
    }
    {   // output: B*D*HW/4 threads
        int n4 = BB * DD * HW / 4;
        k_out<<<dim3((n4 + 255) / 256), dim3(256), 0, stream>>>(cost, gh, gv, out);
    }
}

// Round 3
// 54.034 us; speedup vs baseline: 2.2625x; 1.1817x over previous
//
#include <hip/hip_runtime.h>

#define BB 4
#define DD 81
#define HH 256
#define WW 256
#define HW (HH*WW)
#define N4 (BB*HW/4)      // 65536 float4-outputs for cmin
#define SPLIT 3
#define CHUNK 27          // 3*27 = 81

// ---------------------------------------------------------------------------
// Kernel 1a: partial min over a 27-wide chunk of D.
// partial layout: [SPLIT][B*HW] floats, lives in the tail of d_out.
// ---------------------------------------------------------------------------
__global__ void k_cmin_part(const float* __restrict__ cost, float* __restrict__ partial) {
    int i = blockIdx.x * blockDim.x + threadIdx.x;   // [0, SPLIT*N4)
    if (i >= SPLIT * N4) return;
    int s   = i / N4;
    int r   = i - s * N4;            // float4 index within [B*HW/4]
    int b   = r / (HW / 4);
    int hw4 = r % (HW / 4);
    const float4* src = reinterpret_cast<const float4*>(cost + (size_t)b * DD * HW
                                                        + (size_t)(s * CHUNK) * HW) + hw4;
    float4 m = {3.4e38f, 3.4e38f, 3.4e38f, 3.4e38f};
    #pragma unroll 9
    for (int d = 0; d < CHUNK; ++d) {
        float4 v = src[(size_t)d * (HW / 4)];
        m.x = fminf(m.x, v.x);
        m.y = fminf(m.y, v.y);
        m.z = fminf(m.z, v.z);
        m.w = fminf(m.w, v.w);
    }
    reinterpret_cast<float4*>(partial)[i] = m;
}

// ---------------------------------------------------------------------------
// Kernel 1b: combine the 3 partials -> cmin
// ---------------------------------------------------------------------------
__global__ void k_combine(const float* __restrict__ partial, float* __restrict__ cmin) {
    int i = blockIdx.x * blockDim.x + threadIdx.x;   // [0, N4)
    if (i >= N4) return;
    const float4* p = reinterpret_cast<const float4*>(partial);
    float4 a = p[i], b = p[N4 + i], c = p[2 * N4 + i];
    float4 m;
    m.x = fminf(fminf(a.x, b.x), c.x);
    m.y = fminf(fminf(a.y, b.y), c.y);
    m.z = fminf(fminf(a.z, b.z), c.z);
    m.w = fminf(fminf(a.w, b.w), c.w);
    reinterpret_cast<float4*>(cmin)[i] = m;
}

// ---------------------------------------------------------------------------
// Wave-parallel bidirectional linear-recurrence scan over 256 elements.
// m_j = c_j + e_j*m_{j-1}; operator (a,b) composes as cur∘prev =
// (a_c*a_p, a_c*b_p + b_c). g_j = e_j*m_{j-1} accumulated for both directions.
// ---------------------------------------------------------------------------
__device__ __forceinline__ void wave_scan_bidir(
        int lane, const float c[4], const float ef[4], const float eb[4], float g[4]) {
    float A = 1.f, B = 0.f;
    #pragma unroll
    for (int j = 0; j < 4; ++j) { B = ef[j] * B + c[j]; A = ef[j] * A; }
    #pragma unroll
    for (int d = 1; d < 64; d <<= 1) {
        float Ap = __shfl_up(A, d);
        float Bp = __shfl_up(B, d);
        if (lane >= d) { B = A * Bp + B; A = A * Ap; }
    }
    float m_in = __shfl_up(B, 1);
    if (lane == 0) m_in = 0.f;
    float m = m_in;
    #pragma unroll
    for (int j = 0; j < 4; ++j) { float t = ef[j] * m; g[j] = t; m = c[j] + t; }

    A = 1.f; B = 0.f;
    #pragma unroll
    for (int j = 3; j >= 0; --j) { B = eb[j] * B + c[j]; A = eb[j] * A; }
    #pragma unroll
    for (int d = 1; d < 64; d <<= 1) {
        float An = __shfl_down(A, d);
        float Bn = __shfl_down(B, d);
        if (lane + d < 64) { B = A * Bn + B; A = A * An; }
    }
    m_in = __shfl_down(B, 1);
    if (lane == 63) m_in = 0.f;
    m = m_in;
    #pragma unroll
    for (int j = 3; j >= 0; --j) { float t = eb[j] * m; g[j] += t; m = c[j] + t; }
}

// ---------------------------------------------------------------------------
// Kernel 2: waves [0,1024): horizontal rows (ch 0 fwd, ch 1 bwd) -> gh
//           waves [1024,2048): vertical cols (ch 2 down, ch 3 up) -> gv
// ---------------------------------------------------------------------------
__global__ void k_scan(const float* __restrict__ cmin, const float* __restrict__ edge,
                       float* __restrict__ gh, float* __restrict__ gv) {
    int tid  = blockIdx.x * blockDim.x + threadIdx.x;
    int wave = tid >> 6;
    int lane = tid & 63;
    float c[4], ef[4], eb[4], g[4];
    if (wave < BB * HH) {
        int b = wave / HH, h = wave % HH;
        size_t row = (size_t)b * HW + (size_t)h * WW;
        float4 c4  = reinterpret_cast<const float4*>(cmin + row)[lane];
        float4 f4  = reinterpret_cast<const float4*>(edge + ((size_t)b * 4 + 0) * HW + (size_t)h * WW)[lane];
        float4 b4  = reinterpret_cast<const float4*>(edge + ((size_t)b * 4 + 1) * HW + (size_t)h * WW)[lane];
        c[0]=c4.x; c[1]=c4.y; c[2]=c4.z; c[3]=c4.w;
        ef[0]=f4.x; ef[1]=f4.y; ef[2]=f4.z; ef[3]=f4.w;
        eb[0]=b4.x; eb[1]=b4.y; eb[2]=b4.z; eb[3]=b4.w;
        wave_scan_bidir(lane, c, ef, eb, g);
        float4 o = {g[0], g[1], g[2], g[3]};
        reinterpret_cast<float4*>(gh + row)[lane] = o;
    } else if (wave < 2 * BB * HH) {
        int wv = wave - BB * HH;
        int b = wv / WW, w = wv % WW;
        const float* cm = cmin + (size_t)b * HW + w;
        const float* e2 = edge + ((size_t)b * 4 + 2) * HW + w;
        const float* e3 = edge + ((size_t)b * 4 + 3) * HW + w;
        int r0 = lane * 4;
        #pragma unroll
        for (int j = 0; j < 4; ++j) {
            size_t off = (size_t)(r0 + j) * WW;
            c[j]  = cm[off];
            ef[j] = e2[off];
            eb[j] = e3[off];
        }
        wave_scan_bidir(lane, c, ef, eb, g);
        float* go = gv + (size_t)b * HW + w;
        #pragma unroll
        for (int j = 0; j < 4; ++j) go[(size_t)(r0 + j) * WW] = g[j];
    }
}

// ---------------------------------------------------------------------------
// Kernel 3: out[b,d,h,w] = 4*cost[b,d,h,w] + gh[b,h,w] + gv[b,h,w]
// ---------------------------------------------------------------------------
__global__ void k_out(const float* __restrict__ cost, const float* __restrict__ gh,
                      const float* __restrict__ gv, float* __restrict__ out) {
    int i = blockIdx.x * blockDim.x + threadIdx.x;
    const int n4 = BB * DD * HW / 4;
    if (i >= n4) return;
    int base = i << 2;
    int b    = base / (DD * HW);
    int rem  = base % (DD * HW);
    int hw   = rem % HW;
    float4 c = reinterpret_cast<const float4*>(cost)[i];
    int gi   = (b * HW + hw) >> 2;
    float4 a = reinterpret_cast<const float4*>(gh)[gi];
    float4 v = reinterpret_cast<const float4*>(gv)[gi];
    float4 o;
    o.x = 4.f * c.x + a.x + v.x;
    o.y = 4.f * c.y + a.y + v.y;
    o.z = 4.f * c.z + a.z + v.z;
    o.w = 4.f * c.w + a.w + v.w;
    reinterpret_cast<float4*>(out)[i] = o;
}

extern "C" void kernel_launch(void* const* d_in, const int* in_sizes, int n_in,
                              void* d_out, int out_size, void* d_ws, size_t ws_size,
                              hipStream_t stream) {
    const float* cost = (const float*)d_in[0];
    const float* edge = (const float*)d_in[1];
    float* out = (float*)d_out;

    // ws layout: gh [1MB] | gv [1MB] | cmin [1MB]
    float* gh   = (float*)d_ws;
    float* gv   = gh + (size_t)BB * HW;
    float* cmin = gv + (size_t)BB * HW;
    // partials [SPLIT][B*HW] live in the tail of d_out (dead until k_out
    // rewrites the whole buffer at the end).
    float* partial = out + (size_t)out_size - (size_t)SPLIT * BB * HW;

    {   // 1a: partial mins, SPLIT*N4 = 196608 threads (768 blocks)
        int n = SPLIT * N4;
        k_cmin_part<<<dim3((n + 255) / 256), dim3(256), 0, stream>>>(cost, partial);
    }
    {   // 1b: combine partials -> cmin
        k_combine<<<dim3((N4 + 255) / 256), dim3(256), 0, stream>>>(partial, cmin);
    }
    {   // 2: scans, 2048 waves = 131072 threads
        int n = 2 * BB * HH * 64;
        k_scan<<<dim3((n + 255) / 256), dim3(256), 0, stream>>>(cmin, edge, gh, gv);
    }
    {   // 3: output
        int n4 = BB * DD * HW / 4;
        k_out<<<dim3((n4 + 255) / 256), dim3(256), 0, stream>>>(cost, gh, gv, out);
    }
}